// Round 18
// baseline (246.175 us; speedup 1.0000x reference)
//
#include <hip/hip_runtime.h>
#include <math.h>

// Problem constants (B=2,S=2048,D=1024, N_EXP=8, TOP_K=2, CAP_FACTOR=1.25)
#define NTOK   4096          // B*S
#define DIM    1024
#define NEXP   8
#define CAP    1280          // int(4096*2*1.25/8)
#define MROW   (NEXP * CAP)  // 10240 floats per token's mask row

// d_out layout: gates[4096][2] | exp_mask[4096][8][1280] | exp_batches[8][1280][1024]
#define OUT_MASK_OFF   ((size_t)NTOK*2)                       // 8192
#define OUT_BATCH_OFF  (OUT_MASK_OFF + (size_t)NTOK*NEXP*CAP) // + 41943040

typedef float f4 __attribute__((ext_vector_type(4)));

// ---------------- Kernel 1: gating — one wave per token, no barriers ----------------
__global__ __launch_bounds__(256) void gate_kernel(
    const float* __restrict__ x, const float* __restrict__ Wg,
    float* __restrict__ gates_out,
    int* __restrict__ e0a, int* __restrict__ e1a,
    float* __restrict__ g0a, float* __restrict__ g1a)
{
    const int wave = threadIdx.x >> 6;
    const int lane = threadIdx.x & 63;
    const int t    = blockIdx.x * 4 + wave;          // 1024 blocks * 4 waves = 4096

    const f4* xr = (const f4*)(x + (size_t)t * DIM); // 256 f4 per row
    f4 xv[4];
#pragma unroll
    for (int p = 0; p < 4; ++p) xv[p] = xr[p * 64 + lane];

    float acc[NEXP];
#pragma unroll
    for (int e = 0; e < NEXP; ++e) {
        const f4* wr = (const f4*)(Wg + (size_t)e * DIM);
        float a = 0.f;
#pragma unroll
        for (int p = 0; p < 4; ++p) {
            const f4 w = wr[p * 64 + lane];
            a += xv[p].x * w.x + xv[p].y * w.y + xv[p].z * w.z + xv[p].w * w.w;
        }
        acc[e] = a;
    }

    // 64-lane butterfly reduce (all lanes end with full sums)
#pragma unroll
    for (int off = 32; off >= 1; off >>= 1) {
#pragma unroll
        for (int e = 0; e < NEXP; ++e)
            acc[e] += __shfl_xor(acc[e], off);
    }

    if (lane == 0) {
        // top-2, lower index wins ties (matches lax.top_k)
        float best = -INFINITY, second = -INFINITY;
        int b0 = 0, b1 = 0;
#pragma unroll
        for (int e = 0; e < NEXP; ++e) {
            const float v = acc[e];
            if (v > best)        { second = best; b1 = b0; best = v; b0 = e; }
            else if (v > second) { second = v; b1 = e; }
        }
        const float e1v = __expf(second - best);
        const float inv = 1.0f / (1.0f + e1v);
        const float g0 = inv, g1 = e1v * inv;

        gates_out[(size_t)t * 2]     = g0;
        gates_out[(size_t)t * 2 + 1] = g1;
        e0a[t] = b0; e1a[t] = b1;
        g0a[t] = g0; g1a[t] = g1;
    }
}

// ------- Kernel 2: serial-order position scan — LDS counters (rule-#20 fix kept) -------
__global__ __launch_bounds__(256) void scan_kernel(
    const int* __restrict__ e0a, const int* __restrict__ e1a,
    int* __restrict__ pos0a, int* __restrict__ pos1a,
    int* __restrict__ inv_out)
{
    __shared__ int invs[NEXP * CAP];          // 40 KB
    __shared__ int runs[256][9];              // 9 KB (pad col -> bank-conflict-free)
    __shared__ unsigned wtot[4][4];

    const int tid  = threadIdx.x;
    const int wave = tid >> 6;
    const int lane = tid & 63;

    for (int i = tid; i < NEXP * CAP; i += 256) invs[i] = -1;

    // Thread tid owns tokens [tid*16, tid*16+16) == slots [tid*32, tid*32+32)
    const int tok0 = tid * 16;
    int ea[16], eb[16];
    {
        const int4* va = (const int4*)(e0a + tok0);
        const int4* vb = (const int4*)(e1a + tok0);
#pragma unroll
        for (int q = 0; q < 4; ++q) {
            int4 a = va[q], b = vb[q];
            ea[4*q] = a.x; ea[4*q+1] = a.y; ea[4*q+2] = a.z; ea[4*q+3] = a.w;
            eb[4*q] = b.x; eb[4*q+1] = b.y; eb[4*q+2] = b.z; eb[4*q+3] = b.w;
        }
    }

    // histogram: static indices only (compare-add over all 8 experts)
    int cnt[NEXP];
#pragma unroll
    for (int e = 0; e < NEXP; ++e) cnt[e] = 0;
#pragma unroll
    for (int j = 0; j < 16; ++j) {
#pragma unroll
        for (int e = 0; e < NEXP; ++e)
            cnt[e] += (ea[j] == e ? 1 : 0) + (eb[j] == e ? 1 : 0);
    }

    // pack 8 counters into 4 x (2x16-bit).  Totals <= 8192 < 2^16 -> no carry ever.
    unsigned pk[4];
#pragma unroll
    for (int q = 0; q < 4; ++q)
        pk[q] = (unsigned)cnt[2*q] | ((unsigned)cnt[2*q+1] << 16);
    const unsigned my0 = pk[0], my1 = pk[1], my2 = pk[2], my3 = pk[3];

    // wave-inclusive scan, no barriers
#pragma unroll
    for (int off = 1; off < 64; off <<= 1) {
        unsigned n0 = __shfl_up((int)pk[0], off);
        unsigned n1 = __shfl_up((int)pk[1], off);
        unsigned n2 = __shfl_up((int)pk[2], off);
        unsigned n3 = __shfl_up((int)pk[3], off);
        if (lane >= off) { pk[0] += n0; pk[1] += n1; pk[2] += n2; pk[3] += n3; }
    }

    if (lane == 63) {
#pragma unroll
        for (int q = 0; q < 4; ++q) wtot[wave][q] = pk[q];
    }
    __syncthreads();   // also covers invs init

    // add totals of earlier waves -> global inclusive; subtract own -> exclusive
#pragma unroll
    for (int w = 0; w < 4; ++w) {
        if (w < wave) {
            pk[0] += wtot[w][0]; pk[1] += wtot[w][1];
            pk[2] += wtot[w][2]; pk[3] += wtot[w][3];
        }
    }
    pk[0] -= my0; pk[1] -= my1; pk[2] -= my2; pk[3] -= my3;

    // running counters in LDS (native dynamic addressing, no scratch)
    int* run = runs[tid];
#pragma unroll
    for (int q = 0; q < 4; ++q) {
        run[2*q]   = (int)(pk[q] & 0xFFFFu);
        run[2*q+1] = (int)(pk[q] >> 16);
    }

    int p0r[16], p1r[16];
#pragma unroll
    for (int j = 0; j < 16; ++j) {
        const int tok = tok0 + j;
        int e = ea[j];                 // k=0 slot first (token-major, k-minor order)
        int p = run[e]; run[e] = p + 1;
        p0r[j] = p;
        if (p < CAP) invs[e * CAP + p] = tok;
        e = eb[j];
        p = run[e]; run[e] = p + 1;
        p1r[j] = p;
        if (p < CAP) invs[e * CAP + p] = tok;
    }

#pragma unroll
    for (int q = 0; q < 4; ++q) {
        ((int4*)(pos0a + tok0))[q] = make_int4(p0r[4*q], p0r[4*q+1], p0r[4*q+2], p0r[4*q+3]);
        ((int4*)(pos1a + tok0))[q] = make_int4(p1r[4*q], p1r[4*q+1], p1r[4*q+2], p1r[4*q+3]);
    }
    __syncthreads();

    for (int i = tid; i < NEXP * CAP / 4; i += 256)
        ((int4*)inv_out)[i] = ((const int4*)invs)[i];
}

// ------- Kernel 3: CALIBRATION PROBE — fill_batch body executed TWICE -------
// Purpose: measure the user-kernel store rate to d_out directly. The extra rep
// adds exactly 252 MB of traffic; Δtotal reveals the effective BW:
//   Δ ≈ +38 us -> ~6.6 TB/s (writer already at fill speed)
//   Δ ≈ +100 us -> ~2.5 TB/s (store path is the headroom)
// asm memory clobber between reps blocks dead-store elimination.
#define FILL_BLK   2560
#define BATCH_BLK  2560                    // 10240 rows / 4
#define W_BLOCKS   (FILL_BLK + BATCH_BLK)  // 5120
__global__ __launch_bounds__(256) void fill_batch_kernel(
    const int* __restrict__ inv, const float* __restrict__ x,
    float* __restrict__ mask_out, float* __restrict__ batch_out)
{
    const int tid = threadIdx.x;

    for (int rep = 0; rep < 2; ++rep) {
        if (blockIdx.x < FILL_BLK) {
            f4* dst = (f4*)mask_out + (size_t)blockIdx.x * 4096 + tid;
#pragma unroll
            for (int it = 0; it < 16; ++it)
                dst[it * 256] = (f4)(0.f);                   // pure store stream
        } else {
            // 4 batch rows: issue all gathers first (MLP), then store.
            const int grp = blockIdx.x - FILL_BLK;           // 0..2559
            const int4 tk = ((const int4*)inv)[grp];
            const int toks[4] = { tk.x, tk.y, tk.z, tk.w };
            const int base = grp * 4;
            f4 v[4];
#pragma unroll
            for (int i = 0; i < 4; ++i) {
                v[i] = (f4)(0.f);
                if (toks[i] >= 0)
                    v[i] = ((const f4*)(x + (size_t)toks[i] * DIM))[tid];
            }
#pragma unroll
            for (int i = 0; i < 4; ++i)
                ((f4*)(batch_out + (size_t)(base + i) * DIM))[tid] = v[i];
        }
        asm volatile("" ::: "memory");   // block dead-store elimination of rep 0
    }
}

// ------- Kernel 4: S — scatter the 8192 gate values into the zeroed mask -------
// One thread per token; 2 scattered 4B stores. Runs AFTER the fill (stream order).
__global__ __launch_bounds__(256) void scatter_kernel(
    const int* __restrict__ e0a, const int* __restrict__ e1a,
    const int* __restrict__ pos0a, const int* __restrict__ pos1a,
    const float* __restrict__ g0a, const float* __restrict__ g1a,
    float* __restrict__ mask_out)
{
    const int t = blockIdx.x * 256 + threadIdx.x;            // 16 blocks -> 4096
    const int e0 = e0a[t], e1 = e1a[t];
    const int p0 = pos0a[t], p1 = pos1a[t];

    float* row = mask_out + (size_t)t * MROW;
    if (p0 < CAP) row[e0 * CAP + p0] = g0a[t];
    if (p1 < CAP) row[e1 * CAP + p1] = g1a[t];
}

extern "C" void kernel_launch(void* const* d_in, const int* in_sizes, int n_in,
                              void* d_out, int out_size, void* d_ws, size_t ws_size,
                              hipStream_t stream)
{
    const float* x  = (const float*)d_in[0];
    const float* Wg = (const float*)d_in[1];

    float* out   = (float*)d_out;
    float* gates = out;
    float* mask  = out + OUT_MASK_OFF;
    float* batch = out + OUT_BATCH_OFF;

    int* wsi = (int*)d_ws;
    int*   e0a  = wsi;
    int*   e1a  = wsi + NTOK;
    float* g0a  = (float*)(wsi + 2 * NTOK);
    float* g1a  = (float*)(wsi + 3 * NTOK);
    int*   p0a  = wsi + 4 * NTOK;
    int*   p1a  = wsi + 5 * NTOK;
    int*   inv  = wsi + 6 * NTOK;          // NEXP*CAP ints

    gate_kernel      <<<NTOK / 4, 256, 0, stream>>>(x, Wg, gates, e0a, e1a, g0a, g1a);
    scan_kernel      <<<1, 256, 0, stream>>>(e0a, e1a, p0a, p1a, inv);
    fill_batch_kernel<<<W_BLOCKS, 256, 0, stream>>>(inv, x, mask, batch);
    scatter_kernel   <<<NTOK / 256, 256, 0, stream>>>(e0a, e1a, p0a, p1a, g0a, g1a, mask);
}

// Round 20
// 227.268 us; speedup vs baseline: 1.0832x; 1.0832x over previous
//
#include <hip/hip_runtime.h>
#include <math.h>

// Problem constants (B=2,S=2048,D=1024, N_EXP=8, TOP_K=2, CAP_FACTOR=1.25)
#define NTOK   4096          // B*S
#define DIM    1024
#define NEXP   8
#define CAP    1280          // int(4096*2*1.25/8)
#define MROW   (NEXP * CAP)  // 10240 floats per token's mask row

// d_out layout: gates[4096][2] | exp_mask[4096][8][1280] | exp_batches[8][1280][1024]
#define OUT_MASK_OFF   ((size_t)NTOK*2)                       // 8192
#define OUT_BATCH_OFF  (OUT_MASK_OFF + (size_t)NTOK*NEXP*CAP) // + 41943040

typedef float f4 __attribute__((ext_vector_type(4)));

// ---------------- Kernel 1: gating — one wave per token, no barriers ----------------
__global__ __launch_bounds__(256) void gate_kernel(
    const float* __restrict__ x, const float* __restrict__ Wg,
    float* __restrict__ gates_out,
    int* __restrict__ e0a, int* __restrict__ e1a,
    float* __restrict__ g0a, float* __restrict__ g1a)
{
    const int wave = threadIdx.x >> 6;
    const int lane = threadIdx.x & 63;
    const int t    = blockIdx.x * 4 + wave;          // 1024 blocks * 4 waves = 4096

    const f4* xr = (const f4*)(x + (size_t)t * DIM); // 256 f4 per row
    f4 xv[4];
#pragma unroll
    for (int p = 0; p < 4; ++p) xv[p] = xr[p * 64 + lane];

    float acc[NEXP];
#pragma unroll
    for (int e = 0; e < NEXP; ++e) {
        const f4* wr = (const f4*)(Wg + (size_t)e * DIM);
        float a = 0.f;
#pragma unroll
        for (int p = 0; p < 4; ++p) {
            const f4 w = wr[p * 64 + lane];
            a += xv[p].x * w.x + xv[p].y * w.y + xv[p].z * w.z + xv[p].w * w.w;
        }
        acc[e] = a;
    }

    // 64-lane butterfly reduce (all lanes end with full sums)
#pragma unroll
    for (int off = 32; off >= 1; off >>= 1) {
#pragma unroll
        for (int e = 0; e < NEXP; ++e)
            acc[e] += __shfl_xor(acc[e], off);
    }

    if (lane == 0) {
        // top-2, lower index wins ties (matches lax.top_k)
        float best = -INFINITY, second = -INFINITY;
        int b0 = 0, b1 = 0;
#pragma unroll
        for (int e = 0; e < NEXP; ++e) {
            const float v = acc[e];
            if (v > best)        { second = best; b1 = b0; best = v; b0 = e; }
            else if (v > second) { second = v; b1 = e; }
        }
        const float e1v = __expf(second - best);
        const float inv = 1.0f / (1.0f + e1v);
        const float g0 = inv, g1 = e1v * inv;

        gates_out[(size_t)t * 2]     = g0;
        gates_out[(size_t)t * 2 + 1] = g1;
        e0a[t] = b0; e1a[t] = b1;
        g0a[t] = g0; g1a[t] = g1;
    }
}

// ------- Kernel 2: serial-order position scan — LDS counters (rule-#20 fix) -------
// Runtime-indexed per-thread arrays would go to scratch; histogram is static
// compare-add, running counters live in LDS (native dynamic addressing).
__global__ __launch_bounds__(256) void scan_kernel(
    const int* __restrict__ e0a, const int* __restrict__ e1a,
    int* __restrict__ pos0a, int* __restrict__ pos1a,
    int* __restrict__ inv_out)
{
    __shared__ int invs[NEXP * CAP];          // 40 KB
    __shared__ int runs[256][9];              // 9 KB (pad col -> bank-conflict-free)
    __shared__ unsigned wtot[4][4];

    const int tid  = threadIdx.x;
    const int wave = tid >> 6;
    const int lane = tid & 63;

    for (int i = tid; i < NEXP * CAP; i += 256) invs[i] = -1;

    // Thread tid owns tokens [tid*16, tid*16+16) == slots [tid*32, tid*32+32)
    const int tok0 = tid * 16;
    int ea[16], eb[16];
    {
        const int4* va = (const int4*)(e0a + tok0);
        const int4* vb = (const int4*)(e1a + tok0);
#pragma unroll
        for (int q = 0; q < 4; ++q) {
            int4 a = va[q], b = vb[q];
            ea[4*q] = a.x; ea[4*q+1] = a.y; ea[4*q+2] = a.z; ea[4*q+3] = a.w;
            eb[4*q] = b.x; eb[4*q+1] = b.y; eb[4*q+2] = b.z; eb[4*q+3] = b.w;
        }
    }

    // histogram: static indices only (compare-add over all 8 experts)
    int cnt[NEXP];
#pragma unroll
    for (int e = 0; e < NEXP; ++e) cnt[e] = 0;
#pragma unroll
    for (int j = 0; j < 16; ++j) {
#pragma unroll
        for (int e = 0; e < NEXP; ++e)
            cnt[e] += (ea[j] == e ? 1 : 0) + (eb[j] == e ? 1 : 0);
    }

    // pack 8 counters into 4 x (2x16-bit).  Totals <= 8192 < 2^16 -> no carry ever.
    unsigned pk[4];
#pragma unroll
    for (int q = 0; q < 4; ++q)
        pk[q] = (unsigned)cnt[2*q] | ((unsigned)cnt[2*q+1] << 16);
    const unsigned my0 = pk[0], my1 = pk[1], my2 = pk[2], my3 = pk[3];

    // wave-inclusive scan, no barriers
#pragma unroll
    for (int off = 1; off < 64; off <<= 1) {
        unsigned n0 = __shfl_up((int)pk[0], off);
        unsigned n1 = __shfl_up((int)pk[1], off);
        unsigned n2 = __shfl_up((int)pk[2], off);
        unsigned n3 = __shfl_up((int)pk[3], off);
        if (lane >= off) { pk[0] += n0; pk[1] += n1; pk[2] += n2; pk[3] += n3; }
    }

    if (lane == 63) {
#pragma unroll
        for (int q = 0; q < 4; ++q) wtot[wave][q] = pk[q];
    }
    __syncthreads();   // also covers invs init

    // add totals of earlier waves -> global inclusive; subtract own -> exclusive
#pragma unroll
    for (int w = 0; w < 4; ++w) {
        if (w < wave) {
            pk[0] += wtot[w][0]; pk[1] += wtot[w][1];
            pk[2] += wtot[w][2]; pk[3] += wtot[w][3];
        }
    }
    pk[0] -= my0; pk[1] -= my1; pk[2] -= my2; pk[3] -= my3;

    // running counters in LDS (native dynamic addressing, no scratch)
    int* run = runs[tid];
#pragma unroll
    for (int q = 0; q < 4; ++q) {
        run[2*q]   = (int)(pk[q] & 0xFFFFu);
        run[2*q+1] = (int)(pk[q] >> 16);
    }

    int p0r[16], p1r[16];
#pragma unroll
    for (int j = 0; j < 16; ++j) {
        const int tok = tok0 + j;
        int e = ea[j];                 // k=0 slot first (token-major, k-minor order)
        int p = run[e]; run[e] = p + 1;
        p0r[j] = p;
        if (p < CAP) invs[e * CAP + p] = tok;
        e = eb[j];
        p = run[e]; run[e] = p + 1;
        p1r[j] = p;
        if (p < CAP) invs[e * CAP + p] = tok;
    }

#pragma unroll
    for (int q = 0; q < 4; ++q) {
        ((int4*)(pos0a + tok0))[q] = make_int4(p0r[4*q], p0r[4*q+1], p0r[4*q+2], p0r[4*q+3]);
        ((int4*)(pos1a + tok0))[q] = make_int4(p1r[4*q], p1r[4*q+1], p1r[4*q+2], p1r[4*q+3]);
    }
    __syncthreads();

    for (int i = tid; i < NEXP * CAP / 4; i += 256)
        ((int4*)inv_out)[i] = ((const int4*)invs)[i];
}

// ------- Kernel 3: writer — best-measured config (R11 geometry, patch-in-stream) -------
// blocks 0..2047:      2 mask rows each (80 KB, 20 f4-stores/thread, plain stores,
//                      <=2 gate values patched in-register -> no scatter pass)
// blocks 2048..4607:   4 batch rows each (4 independent gathers, then 4 stores)
#define MASK_BLK   2048
#define BATCH_BLK  2560                    // 10240 rows / 4
#define WRITER_BLOCKS (MASK_BLK + BATCH_BLK)   // 4608
__global__ __launch_bounds__(256) void writer_kernel(
    const int* __restrict__ e0a, const int* __restrict__ e1a,
    const int* __restrict__ pos0a, const int* __restrict__ pos1a,
    const float* __restrict__ g0a, const float* __restrict__ g1a,
    const int* __restrict__ inv, const float* __restrict__ x,
    float* __restrict__ mask_out, float* __restrict__ batch_out)
{
    const int tid = threadIdx.x;

    if (blockIdx.x < MASK_BLK) {
        const int t0 = blockIdx.x * 2;
#pragma unroll
        for (int r = 0; r < 2; ++r) {
            const int t  = t0 + r;
            const int e0 = e0a[t], e1 = e1a[t];
            const int p0 = pos0a[t], p1 = pos1a[t];
            const float g0 = g0a[t], g1 = g1a[t];

            const int o0 = e0 * CAP + p0;
            const int o1 = e1 * CAP + p1;
            const int q0 = (p0 < CAP) ? (o0 >> 2) : -1;      // f4 index of patch 0
            const int c0 = o0 & 3;
            const int q1 = (p1 < CAP) ? (o1 >> 2) : -1;
            const int c1 = o1 & 3;

            f4* row = (f4*)(mask_out + (size_t)t * MROW);    // 2560 f4 per row
#pragma unroll
            for (int it = 0; it < MROW / 1024; ++it) {       // 10 iterations
                const int f4i = it * 256 + tid;
                f4 v = (f4)(0.f);
                if (f4i == q0) {                             // at most 1 lane/row
                    v.x = (c0 == 0) ? g0 : 0.f;
                    v.y = (c0 == 1) ? g0 : 0.f;
                    v.z = (c0 == 2) ? g0 : 0.f;
                    v.w = (c0 == 3) ? g0 : 0.f;
                }
                if (f4i == q1) {
                    v.x = (c1 == 0) ? g1 : v.x;
                    v.y = (c1 == 1) ? g1 : v.y;
                    v.z = (c1 == 2) ? g1 : v.z;
                    v.w = (c1 == 3) ? g1 : v.w;
                }
                row[f4i] = v;                                // plain store
            }
        }
    } else {
        // 4 batch rows: issue all gathers first (MLP), then store.
        const int grp = blockIdx.x - MASK_BLK;               // 0..2559
        const int4 tk = ((const int4*)inv)[grp];
        const int toks[4] = { tk.x, tk.y, tk.z, tk.w };
        const int base = grp * 4;
        f4 v[4];
#pragma unroll
        for (int i = 0; i < 4; ++i) {
            v[i] = (f4)(0.f);
            if (toks[i] >= 0)
                v[i] = ((const f4*)(x + (size_t)toks[i] * DIM))[tid];
        }
#pragma unroll
        for (int i = 0; i < 4; ++i)
            ((f4*)(batch_out + (size_t)(base + i) * DIM))[tid] = v[i];
    }
}

extern "C" void kernel_launch(void* const* d_in, const int* in_sizes, int n_in,
                              void* d_out, int out_size, void* d_ws, size_t ws_size,
                              hipStream_t stream)
{
    const float* x  = (const float*)d_in[0];
    const float* Wg = (const float*)d_in[1];

    float* out   = (float*)d_out;
    float* gates = out;
    float* mask  = out + OUT_MASK_OFF;
    float* batch = out + OUT_BATCH_OFF;

    int* wsi = (int*)d_ws;
    int*   e0a  = wsi;
    int*   e1a  = wsi + NTOK;
    float* g0a  = (float*)(wsi + 2 * NTOK);
    float* g1a  = (float*)(wsi + 3 * NTOK);
    int*   p0a  = wsi + 4 * NTOK;
    int*   p1a  = wsi + 5 * NTOK;
    int*   inv  = wsi + 6 * NTOK;          // NEXP*CAP ints

    gate_kernel  <<<NTOK / 4, 256, 0, stream>>>(x, Wg, gates, e0a, e1a, g0a, g1a);
    scan_kernel  <<<1, 256, 0, stream>>>(e0a, e1a, p0a, p1a, inv);
    writer_kernel<<<WRITER_BLOCKS, 256, 0, stream>>>(
        e0a, e1a, p0a, p1a, g0a, g1a, inv, x, mask, batch);
}